// Round 9
// baseline (94.850 us; speedup 1.0000x reference)
//
#include <hip/hip_runtime.h>
#include <cstdint>

typedef __bf16 v8bf __attribute__((ext_vector_type(8)));
typedef float f32x4 __attribute__((ext_vector_type(4)));
typedef int i32x4 __attribute__((ext_vector_type(4)));
typedef uint16_t u16;
typedef uint32_t u32;
typedef u16 ushort8 __attribute__((ext_vector_type(8)));

__device__ __forceinline__ u16 f2bf(float f) {
  u32 u = __float_as_uint(f);
  u += 0x7FFFu + ((u >> 16) & 1u);   // round-to-nearest-even
  return (u16)(u >> 16);
}
__device__ __forceinline__ float bf2f(u16 h) {
  return __uint_as_float((u32)h << 16);
}

#define AS1(p) ((__attribute__((address_space(1))) void*)(p))

__device__ __forceinline__ v8bf ds_read_b128f(u32 addr) {
  i32x4 r;
  asm volatile("ds_read_b128 %0, %1" : "=v"(r) : "v"(addr));
  return __builtin_bit_cast(v8bf, r);
}

// Counted waits: NO clobbers; order pinned with sched_barrier(0) (rule #18).
#define WAITV(N)                                         \
  do {                                                   \
    __builtin_amdgcn_sched_barrier(0);                   \
    asm volatile("s_waitcnt vmcnt(" #N ")");             \
    __builtin_amdgcn_sched_barrier(0);                   \
  } while (0)
#define WAITL(N)                                         \
  do {                                                   \
    __builtin_amdgcn_sched_barrier(0);                   \
    asm volatile("s_waitcnt lgkmcnt(" #N ")");           \
    __builtin_amdgcn_sched_barrier(0);                   \
  } while (0)

// ---------------- K1: fused rownorm + build ----------------
// Block = 64 rows, 512 threads. Pass A: coalesced sweep of the 64x1024 row
// band computing 1/||row|| (wave-local shfl reduce + LDS atomic). Pass B:
// 16 x (64x64 LDS tile) -> Y = bf16(x*rn) row-major and Wt = bf16(x*sqrt(rn))^T.
// Saves the separate rownorm kernel's full 32MB HBM read (pass B re-reads hit L2).
__global__ __launch_bounds__(512) void k_fused(const float* __restrict__ x,
                                               float* __restrict__ rnorm_g,
                                               u16* __restrict__ Y,
                                               u16* __restrict__ Wt) {
  __shared__ float tile[64][65];
  __shared__ float rowacc[64];
  __shared__ float rn[64], sq[64];
  const int i0 = blockIdx.x * 64;
  const int t = threadIdx.x;
  if (t < 64) rowacc[t] = 0.f;
  __syncthreads();
  // Pass A: iter it covers rows 2it, 2it+1; wave w (0..7): row = 2it + (w>>2)
  {
    const int w = t >> 6;
    float s = 0.f;
    int myrow = -1;
    for (int it = 0; it < 32; ++it) {
      const int f = it * 512 + t;          // flat float4 index in 64x256
      const int row = f >> 8;
      const float4 v = ((const float4*)(x + (size_t)i0 * 1024))[f];
      float d = v.x * v.x + v.y * v.y + v.z * v.z + v.w * v.w;
      // wave-uniform row: reduce across 64 lanes, lane 0 accumulates
      #pragma unroll
      for (int off = 32; off > 0; off >>= 1) d += __shfl_down(d, off, 64);
      if ((t & 63) == 0) {
        if (row != myrow) {                // rows change across iters
          if (myrow >= 0) atomicAdd(&rowacc[myrow], s);
          myrow = row; s = 0.f;
        }
        s += d;
      }
    }
    if ((t & 63) == 0 && myrow >= 0) atomicAdd(&rowacc[myrow], s);
    (void)w;
  }
  __syncthreads();
  if (t < 64) {
    const float rv = 1.0f / sqrtf(rowacc[t]);
    rn[t] = rv; sq[t] = sqrtf(rv);
    rnorm_g[i0 + t] = rv;
  }
  __syncthreads();
  // Pass B: 16 column-tiles of 64
  for (int d0 = 0; d0 < 1024; d0 += 64) {
    const int tr = t >> 6;        // 0..7
    const int tc = t & 63;
#pragma unroll
    for (int it = 0; it < 8; ++it) {
      const int r = it * 8 + tr;
      tile[r][tc] = x[(size_t)(i0 + r) * 1024 + d0 + tc];
    }
    __syncthreads();
#pragma unroll
    for (int it = 0; it < 8; ++it) {
      const int r = it * 8 + tr;
      Y[(size_t)(i0 + r) * 1024 + d0 + tc] = f2bf(tile[r][tc] * rn[r]);
    }
#pragma unroll
    for (int it = 0; it < 8; ++it) {
      const int rr = it * 8 + tr;  // d within tile
      Wt[(size_t)(d0 + rr) * 8192 + i0 + tc] = f2bf(tile[tc][rr] * sq[tc]);
    }
    __syncthreads();
  }
}

// ---------------- GEMM: C = A[M][K] * B[N][K]^T, bf16 in, f32 acc ----------------
// BM=BN=128, BK=64, 4 waves (2x2), wave 64x64 = 4x4 frags, 32 MFMA/tile.
// LDS ring-2 (64KB) -> TWO INDEPENDENT BLOCKS PER CU (the untested cell:
// desynced blocks provide the inter-pipe overlap that phase-locked waves
// can't — m114). XOR-swizzle (R4-verified 0 conflicts), clobber-free counted
// vmcnt(8), 8-phase fine interleave with counted lgkm, setprio on MFMA.
// MODE 0: Z = Wt*Wt^T, split-K=16 (2 slices per XCD, L2-resident), bf16 partials.
// MODE 1: out = sigmoid(Y*Ztb^T + x*rn*zdiag), 8 m-panels per XCD.
template <int MODE>
__global__ __launch_bounds__(256, 2) void k_gemm128(
    const u16* __restrict__ A, const u16* __restrict__ B, void* __restrict__ Cv,
    const float* __restrict__ Xf, const float* __restrict__ rnorm,
    const float* __restrict__ zdiag) {
  __shared__ char lds[2][32768] __attribute__((aligned(16)));
  const int tid = threadIdx.x;
  const int wave = tid >> 6;      // 0..3
  const int lane = tid & 63;
  const int wm = wave >> 1, wn = wave & 1;

  int m0, n0, k_start, K, nt;
  int zi = 0, tile = 0;
  if (MODE == 0) {
    // 1024 blocks: xcd=b&7 owns zi slices {2xcd, 2xcd+1}; 64 tiles each
    const int b = blockIdx.x;
    const int r = b >> 3;               // 0..127
    zi = ((b & 7) << 1) | (r >> 6);     // 0..15
    tile = r & 63;
    m0 = (tile >> 3) * 128;
    n0 = (tile & 7) * 128;
    k_start = zi * 512; K = 8192; nt = 8;
  } else {
    // 512 blocks: xcd=b&7 owns 8 m-tiles (1MB Y band + Ztb in L2)
    const int b = blockIdx.x;
    const int r = b >> 3;               // 0..63
    m0 = (((b & 7) << 3) | (r >> 3)) * 128;   // 64 m-tiles
    n0 = (r & 7) * 128;
    k_start = 0; K = 1024; nt = 16;
  }

  f32x4 acc[4][4] = {};

  const int frow = lane & 15;
  const u32 sw0 = (u32)(((lane >> 4) ^ (frow & 7)) << 4);  // swizzled 16B slot

  // staging: rows wave*32 + j*8 + (lane>>3), j=0..3; inverse-swizzled k-chunk
  const int srA = lane >> 3;
  const int swz8 = ((lane & 7) ^ srA) << 3;
  const u16* gA_l = A + (size_t)(m0 + wave * 32 + srA) * K + k_start + swz8;
  const u16* gB_l = B + (size_t)(n0 + wave * 32 + srA) * K + k_start + swz8;

  typedef __attribute__((address_space(3))) char* ldsp;
  ldsp l3 = (ldsp)((__attribute__((address_space(3))) void*)&lds[0][0]);
  const u32 lds0 = (u32)(uintptr_t)l3;

#define STAGE8(buf, kt)                                                        \
  do {                                                                         \
    const size_t _ko = (size_t)(kt) * 64;                                      \
    ldsp _ba = l3 + (buf) * 32768 + wave * 4096;                               \
    ldsp _bb = l3 + (buf) * 32768 + 16384 + wave * 4096;                       \
    _Pragma("unroll")                                                          \
    for (int _j = 0; _j < 4; ++_j)                                             \
      __builtin_amdgcn_global_load_lds(AS1(gA_l + _ko + (size_t)_j * 8 * K),   \
                                       (_ba + _j * 1024), 16, 0, 0);           \
    _Pragma("unroll")                                                          \
    for (int _j = 0; _j < 4; ++_j)                                             \
      __builtin_amdgcn_global_load_lds(AS1(gB_l + _ko + (size_t)_j * 8 * K),   \
                                       (_bb + _j * 1024), 16, 0, 0);           \
  } while (0)

#define MFMA4(ar, barr)                                                        \
  do {                                                                         \
    __builtin_amdgcn_s_setprio(1);                                             \
    acc[_mi][0] = __builtin_amdgcn_mfma_f32_16x16x32_bf16((ar), (barr)[0], acc[_mi][0], 0, 0, 0); \
    acc[_mi][1] = __builtin_amdgcn_mfma_f32_16x16x32_bf16((ar), (barr)[1], acc[_mi][1], 0, 0, 0); \
    acc[_mi][2] = __builtin_amdgcn_mfma_f32_16x16x32_bf16((ar), (barr)[2], acc[_mi][2], 0, 0, 0); \
    acc[_mi][3] = __builtin_amdgcn_mfma_f32_16x16x32_bf16((ar), (barr)[3], acc[_mi][3], 0, 0, 0); \
    __builtin_amdgcn_s_setprio(0);                                             \
  } while (0)

  STAGE8(0, 0);
  STAGE8(1, 1);
  for (int t = 0; t < nt; ++t) {
    const int buf = t & 1;
    if (t < nt - 1) { WAITV(8); } else { WAITV(0); }   // tile t landed; t+1 in flight
    __builtin_amdgcn_s_barrier();
    const u32 bb = lds0 + (u32)buf * 32768;
    const u32 aA = bb + (u32)((wm * 64 + frow) * 128) + sw0;
    const u32 aB = bb + 16384u + (u32)((wn * 64 + frow) * 128) + sw0;
    v8bf a0[4], a1[4], b0[4], b1[4];
    // issue order for counted lgkm (pure-DS, in-order): b0*4, a0[0], b1*4, a1[0]
    b0[0] = ds_read_b128f(aB);
    b0[1] = ds_read_b128f(aB + 2048);
    b0[2] = ds_read_b128f(aB + 4096);
    b0[3] = ds_read_b128f(aB + 6144);
    a0[0] = ds_read_b128f(aA);
    b1[0] = ds_read_b128f(aB ^ 0x40);
    b1[1] = ds_read_b128f((aB + 2048) ^ 0x40);
    b1[2] = ds_read_b128f((aB + 4096) ^ 0x40);
    b1[3] = ds_read_b128f((aB + 6144) ^ 0x40);
    a1[0] = ds_read_b128f(aA ^ 0x40);
    WAITL(5);                                   // b0*, a0[0] ready
    { const int _mi = 0; MFMA4(a0[0], b0); }
    a0[1] = ds_read_b128f(aA + 2048);
    a1[1] = ds_read_b128f((aA + 2048) ^ 0x40);
    WAITL(2);                                   // b1*, a1[0] ready
    { const int _mi = 0; MFMA4(a1[0], b1); }
    a0[2] = ds_read_b128f(aA + 4096);
    a1[2] = ds_read_b128f((aA + 4096) ^ 0x40);
    WAITL(3);                                   // a0[1] ready
    { const int _mi = 1; MFMA4(a0[1], b0); }
    a0[3] = ds_read_b128f(aA + 6144);
    a1[3] = ds_read_b128f((aA + 6144) ^ 0x40);
    WAITL(4);                                   // a1[1] ready
    { const int _mi = 1; MFMA4(a1[1], b1); }
    WAITL(3);                                   // a0[2] ready
    { const int _mi = 2; MFMA4(a0[2], b0); }
    WAITL(2);                                   // a1[2] ready
    { const int _mi = 2; MFMA4(a1[2], b1); }
    WAITL(1);                                   // a0[3] ready
    { const int _mi = 3; MFMA4(a0[3], b0); }
    WAITL(0);                                   // a1[3] ready
    { const int _mi = 3; MFMA4(a1[3], b1); }
    __builtin_amdgcn_s_barrier();               // all waves done with buf
    if (t + 2 < nt) STAGE8(buf, t + 2);         // in flight across tile t+1
  }
#undef STAGE8
#undef MFMA4

  // C/D layout (verified): col = lane&15, row = (lane>>4)*4 + reg
  const int crow = (lane >> 4) * 4;
  const int ccol = lane & 15;
#pragma unroll
  for (int mi = 0; mi < 4; ++mi) {
#pragma unroll
    for (int ni = 0; ni < 4; ++ni) {
      const int rl = wm * 64 + mi * 16 + crow;   // 0..127
      const int cl = wn * 64 + ni * 16 + ccol;   // 0..127
#pragma unroll
      for (int r = 0; r < 4; ++r) {
        float v = acc[mi][ni][r];
        if (MODE == 0) {
          const size_t o = (((size_t)(zi * 64 + tile)) << 14) + (size_t)(rl + r) * 128 + cl;
          ((u16*)Cv)[o] = f2bf(v);               // bf16 partial
        } else {
          const int row = m0 + rl + r;
          const int col = n0 + cl;
          const size_t o = (size_t)row * 1024 + col;
          float z = v + Xf[o] * rnorm[row] * zdiag[col];  // exact diag term
          ((float*)Cv)[o] = 1.0f / (1.0f + __expf(-z));
        }
      }
    }
  }
}

// ---------------- K4: reduce 16 bf16 split-K partials -> bf16 Z (diag -> zdiag f32) ----------------
// partials layout: part[zi][tile=(m>>7)*8+(n>>7)][128][128]
__global__ __launch_bounds__(256) void k_reduce1(const u16* __restrict__ part,
                                                 u16* __restrict__ Ztb,
                                                 float* __restrict__ zdiag) {
  const int v = blockIdx.x * 256 + threadIdx.x;  // 0..131071
  const int base = v * 8;                        // over 1024*1024, 8 at a time
  const int m = base >> 10, nn = base & 1023;
  const size_t po = (((size_t)((m >> 7) * 8 + (nn >> 7))) << 14) +
                    (size_t)(m & 127) * 128 + (nn & 127);
  float s[8] = {0, 0, 0, 0, 0, 0, 0, 0};
#pragma unroll
  for (int p = 0; p < 16; ++p) {
    ushort8 pk = *(const ushort8*)(part + (((size_t)p) << 20) + po);
#pragma unroll
    for (int j = 0; j < 8; ++j) s[j] += bf2f(pk[j]);
  }
  ushort8 o;
#pragma unroll
  for (int j = 0; j < 8; ++j) {
    if (m == nn + j) { zdiag[m] = s[j]; o[j] = 0; }
    else o[j] = f2bf(s[j]);
  }
  *(ushort8*)(Ztb + (size_t)m * 1024 + nn) = o;
}

extern "C" void kernel_launch(void* const* d_in, const int* in_sizes, int n_in,
                              void* d_out, int out_size, void* d_ws, size_t ws_size,
                              hipStream_t stream) {
  const float* x = (const float*)d_in[0];
  float* out = (float*)d_out;
  char* ws = (char*)d_ws;

  // ws layout (~34.1 MB): rnorm | Y | Wt | Ztb | zdiag
  float* rnorm = (float*)ws;                                   // 32 KB
  u16* Y    = (u16*)(ws + (1u << 16));                         // 16 MB
  u16* Wt   = (u16*)(ws + (1u << 16) + (16u << 20));           // 16 MB
  u16* Ztb  = (u16*)(ws + (1u << 16) + (32u << 20));           // 2 MB
  float* zdiag = (float*)(ws + (1u << 16) + (34u << 20));      // 4 KB
  u16* part = (u16*)d_out;  // 16 x 2 MB bf16 split-K partials (32 MB = d_out)

  k_fused<<<128, 512, 0, stream>>>(x, rnorm, Y, Wt);
  // Z[d][e] = sum_i Wt[d][i]*Wt[e][i]: 64 tiles x 16 K-slices = 1024 blocks (4/CU grid, 2/CU resident)
  k_gemm128<0><<<1024, 256, 0, stream>>>(Wt, Wt, part, nullptr, nullptr, nullptr);
  k_reduce1<<<512, 256, 0, stream>>>(part, Ztb, zdiag);
  // out[i][d] = sigmoid( sum_k Y[i][k]*Ztb[d][k] + x[i][d]*rn[i]*zdiag[d] ): 512 blocks (2/CU)
  k_gemm128<1><<<512, 256, 0, stream>>>(Y, Ztb, out, x, rnorm, zdiag);
}

// Round 10
// 78.285 us; speedup vs baseline: 1.2116x; 1.2116x over previous
//
#include <hip/hip_runtime.h>
#include <cstdint>

typedef __bf16 v8bf __attribute__((ext_vector_type(8)));
typedef float f32x4 __attribute__((ext_vector_type(4)));
typedef int i32x4 __attribute__((ext_vector_type(4)));
typedef uint16_t u16;
typedef uint32_t u32;
typedef u16 ushort8 __attribute__((ext_vector_type(8)));

__device__ __forceinline__ u16 f2bf(float f) {
  u32 u = __float_as_uint(f);
  u += 0x7FFFu + ((u >> 16) & 1u);   // round-to-nearest-even
  return (u16)(u >> 16);
}
__device__ __forceinline__ float bf2f(u16 h) {
  return __uint_as_float((u32)h << 16);
}

#define AS1(p) ((__attribute__((address_space(1))) void*)(p))

__device__ __forceinline__ v8bf ds_read_b128f(u32 addr) {
  i32x4 r;
  asm volatile("ds_read_b128 %0, %1" : "=v"(r) : "v"(addr));
  return __builtin_bit_cast(v8bf, r);
}

// Counted waits: NO clobbers; order pinned with sched_barrier(0) (rule #18).
#define WAITV(N)                                         \
  do {                                                   \
    __builtin_amdgcn_sched_barrier(0);                   \
    asm volatile("s_waitcnt vmcnt(" #N ")");             \
    __builtin_amdgcn_sched_barrier(0);                   \
  } while (0)
#define WAITL(N)                                         \
  do {                                                   \
    __builtin_amdgcn_sched_barrier(0);                   \
    asm volatile("s_waitcnt lgkmcnt(" #N ")");           \
    __builtin_amdgcn_sched_barrier(0);                   \
  } while (0)

// ---------------- K1: 1/||x_row|| ----------------
__global__ __launch_bounds__(256) void k_rownorm(const float* __restrict__ x,
                                                 float* __restrict__ rnorm) {
  const int row = blockIdx.x;
  const float4 v = ((const float4*)(x + (size_t)row * 1024))[threadIdx.x];
  float s = v.x * v.x + v.y * v.y + v.z * v.z + v.w * v.w;
#pragma unroll
  for (int off = 32; off > 0; off >>= 1) s += __shfl_down(s, off, 64);
  __shared__ float ps[4];
  if ((threadIdx.x & 63) == 0) ps[threadIdx.x >> 6] = s;
  __syncthreads();
  if (threadIdx.x == 0) {
    float t = ps[0] + ps[1] + ps[2] + ps[3];
    rnorm[row] = 1.0f / sqrtf(t);  // norms ~32, eps clamp never binds
  }
}

// ---------------- K2: build Y = bf16(x*rn) [8192][1024], Wt = bf16(x*sqrt(rn))^T [1024][8192] ----------------
// Z = W^T W (SYRK form): Z[d][e] = sum_i x_id*x_ie*rn_i  — single staged operand.
__global__ __launch_bounds__(256) void k_build(const float* __restrict__ x,
                                               const float* __restrict__ rnorm,
                                               u16* __restrict__ Y,
                                               u16* __restrict__ Wt) {
  __shared__ float tile[64][65];
  __shared__ float rn[64], sq[64];
  const int d0 = blockIdx.x * 64;   // 0..1023
  const int i0 = blockIdx.y * 64;   // 0..8191
  const int tr = threadIdx.x >> 6;  // 0..3
  const int tc = threadIdx.x & 63;
#pragma unroll
  for (int it = 0; it < 16; ++it) {
    int r = it * 4 + tr;
    tile[r][tc] = x[(size_t)(i0 + r) * 1024 + d0 + tc];
  }
  if (threadIdx.x < 64) {
    float rv = rnorm[i0 + threadIdx.x];
    rn[threadIdx.x] = rv;
    sq[threadIdx.x] = sqrtf(rv);
  }
  __syncthreads();
#pragma unroll
  for (int it = 0; it < 16; ++it) {
    int r = it * 4 + tr;
    Y[(size_t)(i0 + r) * 1024 + d0 + tc] = f2bf(tile[r][tc] * rn[r]);
  }
#pragma unroll
  for (int it = 0; it < 16; ++it) {
    int rr = it * 4 + tr;            // d within tile
    Wt[(size_t)(d0 + rr) * 8192 + i0 + tc] = f2bf(tile[tc][rr] * sq[tc]);
  }
}

// ---------------- GEMM: C = A[M][K] * B[N][K]^T, bf16 in, f32 acc ----------------
// BM=256 x BN=128, BK=64, 8 waves (4M x 2N), wave 64x64 = 4x4 frags.
// m201 phase template: per K-tile 2 phases, each {8 ds_read || 3 gload_lds ->
// s_barrier -> lgkmcnt(0) -> setprio(1) -> 16 MFMA -> setprio(0) -> s_barrier}.
// Ring-3 LDS (144KB: per buf A[256][128B]@0 + B[128][128B]@32768), depth-2
// prefetch, counted vmcnt(6) folded before the trailing barrier of phase 1.
// XOR-swizzle (verified 0-conflict): read slot ^= row&7; inverse swizzle on
// the per-lane global source (global_load_lds dest linear) — rule #21.
// MODE 0: Z = Wt*Wt^T, split-K=8 (zi=b&7 -> one K-slice per XCD), bf16 partials.
// MODE 1: out = sigmoid(Y*Ztb^T + x*rn*zdiag), 4 m-panels per XCD.
template <int MODE>
__global__ __launch_bounds__(512, 1) void k_gemm256(
    const u16* __restrict__ A, const u16* __restrict__ B, void* __restrict__ Cv,
    const float* __restrict__ Xf, const float* __restrict__ rnorm,
    const float* __restrict__ zdiag) {
  __shared__ char lds[3 * 49152] __attribute__((aligned(128)));
  const int tid = threadIdx.x;
  const int wave = tid >> 6;      // 0..7
  const int lane = tid & 63;
  const int wm = wave >> 1;       // 0..3  (64-row band)
  const int wn = wave & 1;        // 0..1  (64-col band)

  int m0, n0, k_start, K;
  int zi = 0, tile = 0;
  if (MODE == 0) {
    zi = blockIdx.x & 7;          // K-slice -> XCD (2MB Wt band L2-resident)
    tile = blockIdx.x >> 3;       // 0..31
    m0 = (tile >> 3) * 256;       // 4 m-tiles
    n0 = (tile & 7) * 128;        // 8 n-tiles
    k_start = zi * 1024; K = 8192;
  } else {
    const int b = blockIdx.x;
    m0 = ((b & 7) * 4 + ((b >> 3) & 3)) * 256;  // 4 m-panels per XCD
    n0 = (b >> 5) * 128;
    k_start = 0; K = 1024;
  }
  const int nt = 16;  // k_len 1024 = 16 x BK64 for both

  f32x4 acc[4][4] = {};

  const int frow = lane & 15;
  const u32 sw0 = (u32)(((lane >> 4) ^ (frow & 7)) << 4);  // swizzled 16B slot

  // staging: A rows wave*32+j*8+(lane>>3) j=0..3; B rows wave*16+j*8+(lane>>3) j=0..1
  const int srA = lane >> 3;
  const int swz8 = ((lane & 7) ^ srA) << 3;   // inverse-swizzled k-chunk (elems)
  const u16* gA_l = A + (size_t)(m0 + wave * 32 + srA) * K + k_start + swz8;
  const u16* gB_l = B + (size_t)(n0 + wave * 16 + srA) * K + k_start + swz8;

  typedef __attribute__((address_space(3))) char* ldsp;
  ldsp l3 = (ldsp)((__attribute__((address_space(3))) void*)&lds[0]);
  const u32 lds0 = (u32)(uintptr_t)l3;

#define GLOAD_A(buf, kt, j)                                                    \
  __builtin_amdgcn_global_load_lds(                                            \
      AS1(gA_l + (size_t)(kt) * 64 + (size_t)(j) * 8 * K),                     \
      (l3 + (size_t)(buf) * 49152 + wave * 4096 + (j) * 1024), 16, 0, 0)
#define GLOAD_B(buf, kt, j)                                                    \
  __builtin_amdgcn_global_load_lds(                                            \
      AS1(gB_l + (size_t)(kt) * 64 + (size_t)(j) * 8 * K),                     \
      (l3 + (size_t)(buf) * 49152 + 32768 + wave * 2048 + (j) * 1024), 16, 0, 0)
#define STAGE6(buf, kt)                                                        \
  do {                                                                         \
    GLOAD_A(buf, kt, 0); GLOAD_A(buf, kt, 1);                                  \
    GLOAD_A(buf, kt, 2); GLOAD_A(buf, kt, 3);                                  \
    GLOAD_B(buf, kt, 0); GLOAD_B(buf, kt, 1);                                  \
  } while (0)

#define MFMA16()                                                               \
  do {                                                                         \
    __builtin_amdgcn_s_setprio(1);                                             \
    _Pragma("unroll")                                                          \
    for (int mi = 0; mi < 4; ++mi)                                             \
      _Pragma("unroll")                                                        \
      for (int ni = 0; ni < 4; ++ni)                                           \
        acc[mi][ni] = __builtin_amdgcn_mfma_f32_16x16x32_bf16(af[mi], bf[ni], acc[mi][ni], 0, 0, 0); \
    __builtin_amdgcn_s_setprio(0);                                             \
  } while (0)

  STAGE6(0, 0);
  STAGE6(1, 1);
  WAITV(6);                           // tile 0 landed (tile 1's 6 still in flight)
  __builtin_amdgcn_s_barrier();       // visible to all waves
  int cbuf = 0, nbuf = 2;
  for (int t = 0; t < nt; ++t) {
    const u32 bb = lds0 + (u32)cbuf * 49152;
    const u32 aA = bb + (u32)((wm * 64 + frow) * 128) + sw0;
    const u32 aB = bb + 32768u + (u32)((wn * 64 + frow) * 128) + sw0;
    const bool pf = (t + 2 < nt);
    {  // ---- phase 0 (k-step 0) ----
      v8bf af[4], bf[4];
#pragma unroll
      for (int i = 0; i < 4; ++i) af[i] = ds_read_b128f(aA + i * 2048);
#pragma unroll
      for (int i = 0; i < 4; ++i) bf[i] = ds_read_b128f(aB + i * 2048);
      if (pf) { GLOAD_A(nbuf, t + 2, 0); GLOAD_A(nbuf, t + 2, 1); GLOAD_A(nbuf, t + 2, 2); }
      __builtin_amdgcn_s_barrier();
      WAITL(0);
      MFMA16();
      __builtin_amdgcn_s_barrier();
    }
    {  // ---- phase 1 (k-step 1) ----
      v8bf af[4], bf[4];
#pragma unroll
      for (int i = 0; i < 4; ++i) af[i] = ds_read_b128f((aA + i * 2048) ^ 0x40);
#pragma unroll
      for (int i = 0; i < 4; ++i) bf[i] = ds_read_b128f((aB + i * 2048) ^ 0x40);
      if (pf) { GLOAD_A(nbuf, t + 2, 3); GLOAD_B(nbuf, t + 2, 0); GLOAD_B(nbuf, t + 2, 1); }
      __builtin_amdgcn_s_barrier();
      WAITL(0);
      MFMA16();
      // gate for next tile, then the phase's trailing barrier makes it global
      if (t + 2 < nt) { WAITV(6); }
      else if (t + 1 < nt) { WAITV(0); }
      __builtin_amdgcn_s_barrier();
    }
    cbuf = (cbuf + 1 == 3) ? 0 : cbuf + 1;
    nbuf = (nbuf + 1 == 3) ? 0 : nbuf + 1;
  }
#undef STAGE6
#undef GLOAD_A
#undef GLOAD_B
#undef MFMA16

  // C/D layout (verified): col = lane&15, row = (lane>>4)*4 + reg
  const int crow = (lane >> 4) * 4;
  const int ccol = lane & 15;
#pragma unroll
  for (int mi = 0; mi < 4; ++mi) {
#pragma unroll
    for (int ni = 0; ni < 4; ++ni) {
      const int rl = wm * 64 + mi * 16 + crow;   // 0..255
      const int cl = wn * 64 + ni * 16 + ccol;   // 0..127
#pragma unroll
      for (int r = 0; r < 4; ++r) {
        float v = acc[mi][ni][r];
        if (MODE == 0) {
          const size_t o = (((size_t)(zi * 32 + tile)) << 15) + (size_t)(rl + r) * 128 + cl;
          ((u16*)Cv)[o] = f2bf(v);               // bf16 partial
        } else {
          const int row = m0 + rl + r;
          const int col = n0 + cl;
          const size_t o = (size_t)row * 1024 + col;
          float z = v + Xf[o] * rnorm[row] * zdiag[col];  // exact diag term
          ((float*)Cv)[o] = 1.0f / (1.0f + __expf(-z));
        }
      }
    }
  }
}

// ---------------- K4: reduce 8 bf16 split-K partials -> bf16 Z (diag -> zdiag f32) ----------------
// partials layout: part[zi][tile=(m>>8)*8+(n>>7)][256][128]
__global__ __launch_bounds__(256) void k_reduce1(const u16* __restrict__ part,
                                                 u16* __restrict__ Ztb,
                                                 float* __restrict__ zdiag) {
  const int v = blockIdx.x * 256 + threadIdx.x;  // 0..131071
  const int base = v * 8;                        // over 1024*1024, 8 at a time
  const int m = base >> 10, nn = base & 1023;
  const size_t po = (((size_t)((m >> 8) * 8 + (nn >> 7))) << 15) +
                    (size_t)(m & 255) * 128 + (nn & 127);
  float s[8] = {0, 0, 0, 0, 0, 0, 0, 0};
#pragma unroll
  for (int p = 0; p < 8; ++p) {
    ushort8 pk = *(const ushort8*)(part + (((size_t)p) << 20) + po);
#pragma unroll
    for (int j = 0; j < 8; ++j) s[j] += bf2f(pk[j]);
  }
  ushort8 o;
#pragma unroll
  for (int j = 0; j < 8; ++j) {
    if (m == nn + j) { zdiag[m] = s[j]; o[j] = 0; }
    else o[j] = f2bf(s[j]);
  }
  *(ushort8*)(Ztb + (size_t)m * 1024 + nn) = o;
}

extern "C" void kernel_launch(void* const* d_in, const int* in_sizes, int n_in,
                              void* d_out, int out_size, void* d_ws, size_t ws_size,
                              hipStream_t stream) {
  const float* x = (const float*)d_in[0];
  float* out = (float*)d_out;
  char* ws = (char*)d_ws;

  // ws layout (~34.1 MB): rnorm | Y | Wt | Ztb | zdiag
  float* rnorm = (float*)ws;                                   // 32 KB
  u16* Y    = (u16*)(ws + (1u << 16));                         // 16 MB
  u16* Wt   = (u16*)(ws + (1u << 16) + (16u << 20));           // 16 MB
  u16* Ztb  = (u16*)(ws + (1u << 16) + (32u << 20));           // 2 MB
  float* zdiag = (float*)(ws + (1u << 16) + (34u << 20));      // 4 KB
  u16* part = (u16*)d_out;  // 8 x 2 MB bf16 split-K partials (16 MB of d_out)

  k_rownorm<<<8192, 256, 0, stream>>>(x, rnorm);
  k_build<<<dim3(16, 128), 256, 0, stream>>>(x, rnorm, Y, Wt);
  // Z[d][e] = sum_i Wt[d][i]*Wt[e][i]: 32 tiles (256x128) x 8 K-slices = 256 blocks
  k_gemm256<0><<<256, 512, 0, stream>>>(Wt, Wt, part, nullptr, nullptr, nullptr);
  k_reduce1<<<512, 256, 0, stream>>>(part, Ztb, zdiag);
  // out[i][d] = sigmoid( sum_k Y[i][k]*Ztb[d][k] + x[i][d]*rn[i]*zdiag[d] ): 256 blocks
  k_gemm256<1><<<256, 512, 0, stream>>>(Y, Ztb, out, x, rnorm, zdiag);
}